// Round 13
// baseline (238.705 us; speedup 1.0000x reference)
//
#include <hip/hip_runtime.h>
#include <math.h>

#define N_NODES 100000
#define N_EDGES 1600000
#define HIDDEN 128

// ---- binning geometry ------------------------------------------------------
#define NBINS      256
#define BIN_NODES  391        // 256*391 = 100096 >= 100000
#define HALF_NODES 196        // node-half split for B occupancy (196+195)
#define BIN_CAP_MAX 14336     // preferred cap; runtime-shrinks
#define BIN_CAP_MIN 13056     // below this, fall back
#define CUR_STRIDE 32         // cursors padded to 1 per 128B line
#define A_THREADS  1024
#define A_EPT      8
#define A_EPB      (A_THREADS * A_EPT)                    // 8192 edges/block
#define A_BLOCKS   ((N_EDGES + A_EPB - 1) / A_EPB)        // 196
#define B_THREADS  1024
#define NPAD       100096
#define C_THREADS  1024
#define C_BLOCKS   ((N_EDGES + C_THREADS - 1) / C_THREADS) // 1563

// Fixed-point scale for LDS du accumulation (native ds_add_u32).
#define FP_SCALE   4194304.0f
#define FP_INV     (1.0f / 4194304.0f)

// Record layout: [26:17]=own-local node (9b), [16:0]=other node id (17b).

typedef float vfloat4 __attribute__((ext_vector_type(4)));

// ---------------------------------------------------------------------------
// Kernel Z: zero padded cursors.
// ---------------------------------------------------------------------------
__global__ void zero_cursors_kernel(unsigned* __restrict__ cur) {
    cur[threadIdx.x * CUR_STRIDE] = 0u;
}

// ---------------------------------------------------------------------------
// Kernel A: bin edges (8 edges/thread) + build pos4 with idle capacity.
// ---------------------------------------------------------------------------
__global__ __launch_bounds__(A_THREADS) void bin_edges_kernel(
    const int* __restrict__ eidx,
    const float* __restrict__ pos,
    unsigned* __restrict__ cursors,
    unsigned* __restrict__ region,
    float4* __restrict__ pos4,
    int cap)
{
    __shared__ unsigned cnt[NBINS];
    __shared__ unsigned base[NBINS];
    if (threadIdx.x < NBINS) cnt[threadIdx.x] = 0u;

    {
        int gid = blockIdx.x * A_THREADS + threadIdx.x;
        if (gid < N_NODES)
            pos4[gid] = make_float4(pos[gid * 3 + 0], pos[gid * 3 + 1],
                                    pos[gid * 3 + 2], 0.0f);
    }
    __syncthreads();

    const int eb = blockIdx.x * A_EPB + threadIdx.x * 2;

    bool     val[A_EPT];
    unsigned r[A_EPT], c[A_EPT], br[A_EPT], bc[A_EPT], orow[A_EPT], ocol[A_EPT];

    #pragma unroll
    for (int k = 0; k < A_EPT; k += 2) {
        int e = eb + k * A_THREADS;
        bool v = (e < N_EDGES);
        val[k] = v; val[k + 1] = v;
        if (v) {
            int2 rr = *reinterpret_cast<const int2*>(eidx + e);
            int2 cc = *reinterpret_cast<const int2*>(eidx + N_EDGES + e);
            r[k] = (unsigned)rr.x; r[k + 1] = (unsigned)rr.y;
            c[k] = (unsigned)cc.x; c[k + 1] = (unsigned)cc.y;
        }
    }
    #pragma unroll
    for (int k = 0; k < A_EPT; ++k) {
        if (val[k]) {
            br[k] = r[k] / BIN_NODES;
            bc[k] = c[k] / BIN_NODES;
            orow[k] = atomicAdd(&cnt[br[k]], 1u);
            ocol[k] = atomicAdd(&cnt[bc[k]], 1u);
        }
    }
    __syncthreads();

    if (threadIdx.x < NBINS)
        base[threadIdx.x] =
            atomicAdd(&cursors[threadIdx.x * CUR_STRIDE], cnt[threadIdx.x]);
    __syncthreads();

    #pragma unroll
    for (int k = 0; k < A_EPT; ++k) {
        if (val[k]) {
            region[(size_t)br[k] * cap + base[br[k]] + orow[k]] =
                ((r[k] - br[k] * BIN_NODES) << 17) | c[k];
            region[(size_t)bc[k] * cap + base[bc[k]] + ocol[k]] =
                ((c[k] - bc[k] * BIN_NODES) << 17) | r[k];
        }
    }
}

// ---------------------------------------------------------------------------
// Kernel B: two blocks per bin, int32 fixed-point LDS accumulate (R12).
// ---------------------------------------------------------------------------
__device__ __forceinline__ void proc_rec(unsigned rec, unsigned half,
                                         const float4* __restrict__ posLDS4,
                                         const float4* __restrict__ pos4,
                                         int* __restrict__ acc) {
    unsigned local = rec >> 17;
    unsigned h = (local >= HALF_NODES) ? 1u : 0u;
    if (h != half) return;
    unsigned l = local - half * HALF_NODES;
    unsigned other = rec & 0x1FFFFu;
    float4 s = posLDS4[l];
    float4 p = pos4[other];
    float dx = p.x - s.x;
    float dy = p.y - s.y;
    float dz = p.z - s.z;
    float inv = 1.0f / (sqrtf(dx * dx + dy * dy + dz * dz) + 1e-8f);
    atomicAdd(&acc[l * 3 + 0], __float2int_rn(dx * inv * FP_SCALE));
    atomicAdd(&acc[l * 3 + 1], __float2int_rn(dy * inv * FP_SCALE));
    atomicAdd(&acc[l * 3 + 2], __float2int_rn(dz * inv * FP_SCALE));
}

__global__ __launch_bounds__(B_THREADS) void accumulate_kernel(
    const float4* __restrict__ pos4,
    const unsigned* __restrict__ cursors,
    const unsigned* __restrict__ region,
    int cap,
    float* __restrict__ du,
    float* __restrict__ ang,
    float4* __restrict__ du4)
{
    __shared__ int    acc[HALF_NODES * 3];
    __shared__ float4 posLDS4[HALF_NODES];
    const unsigned b    = blockIdx.x >> 1;
    const unsigned half = blockIdx.x & 1;
    const unsigned g0   = b * BIN_NODES + half * HALF_NODES;
    const int maxh = half ? (BIN_NODES - HALF_NODES) : HALF_NODES;
    const int rem  = (int)N_NODES - (int)g0;
    const unsigned nh = (unsigned)max(0, min(maxh, rem));

    for (int i = threadIdx.x; i < HALF_NODES * 3; i += B_THREADS) acc[i] = 0;
    for (unsigned i = threadIdx.x; i < nh; i += B_THREADS)
        posLDS4[i] = pos4[g0 + i];
    __syncthreads();

    const unsigned n = cursors[b * CUR_STRIDE];
    const unsigned* __restrict__ reg = region + (size_t)b * cap;
    const unsigned n4 = n & ~3u;

    for (unsigned i = threadIdx.x * 4; i < n4; i += B_THREADS * 4) {
        uint4 rc = *reinterpret_cast<const uint4*>(reg + i);
        proc_rec(rc.x, half, posLDS4, pos4, acc);
        proc_rec(rc.y, half, posLDS4, pos4, acc);
        proc_rec(rc.z, half, posLDS4, pos4, acc);
        proc_rec(rc.w, half, posLDS4, pos4, acc);
    }
    for (unsigned i = n4 + threadIdx.x; i < n; i += B_THREADS)
        proc_rec(reg[i], half, posLDS4, pos4, acc);
    __syncthreads();

    for (unsigned i = threadIdx.x; i < nh * 3; i += B_THREADS)
        du[(size_t)g0 * 3 + i] = (float)acc[i] * FP_INV;

    for (unsigned i = threadIdx.x; i < nh; i += B_THREADS) {
        float x = (float)acc[i * 3 + 0] * FP_INV;
        float y = (float)acc[i * 3 + 1] * FP_INV;
        float z = (float)acc[i * 3 + 2] * FP_INV;
        du4[g0 + i] = make_float4(x, y, z, x * x + y * y + z * z);
    }

    for (unsigned j = threadIdx.x; j < nh * 32; j += B_THREADS) {
        unsigned node = j >> 5, c4 = j & 31;
        float x = (float)acc[node * 3 + 0] * FP_INV;
        float y = (float)acc[node * 3 + 1] * FP_INV;
        float z = (float)acc[node * 3 + 2] * FP_INV;
        float a = x * x + y * y + z * z;
        vfloat4 v4 = {a, a, a, a};
        __builtin_nontemporal_store(v4,
            reinterpret_cast<vfloat4*>(ang + (size_t)(g0 + node) * HIDDEN) + c4);
    }
}

// ---------------------------------------------------------------------------
// Kernel C v2: register-sourced, sync-free dihedral fill.
// 16 independent waves/block; each wave computes 64 edge scalars in registers,
// then fills 64 rows in 32 steps: value via __shfl (no memory dependency),
// plain float4 stores, 1KB contiguous per wave instruction.
// N_EDGES % 64 == 0 -> full waves are always fully valid.
// ---------------------------------------------------------------------------
__global__ __launch_bounds__(C_THREADS) void dihedral_kernel(
    const float4* __restrict__ pos4,
    const float4* __restrict__ du4,
    const int* __restrict__ eidx,
    float* __restrict__ dih)
{
    const int lane  = threadIdx.x & 63;
    const int ebase = blockIdx.x * C_THREADS + (threadIdx.x & ~63);
    if (ebase >= N_EDGES) return;   // wave-uniform (tail block idle waves)

    float val;
    {
        int e = ebase + lane;
        int r = eidx[e];
        int c = eidx[N_EDGES + e];
        float4 pr = pos4[r];
        float4 pc = pos4[c];
        float4 vi = du4[r];
        float4 vj = du4[c];

        float dx = pc.x - pr.x, dy = pc.y - pr.y, dz = pc.z - pr.z;
        float inv = 1.0f / (sqrtf(dx * dx + dy * dy + dz * dz) + 1e-8f);
        float ux = dx * inv, uy = dy * inv, uz = dz * inv;

        float a  = vi.x * ux + vi.y * uy + vi.z * uz;
        float b  = vj.x * ux + vj.y * uy + vj.z * uz;
        float vv = vi.x * vj.x + vi.y * vj.y + vi.z * vj.z;
        float uu = ux * ux + uy * uy + uz * uz;

        val = vv - a * b * (2.0f - uu);
    }

    // Fill: rows ebase..ebase+63. Step j writes rows ebase+2j, ebase+2j+1.
    // Lane l -> row (l>>5), column (l&31): lanes 0-31 one row, 32-63 next.
    float4* out = reinterpret_cast<float4*>(dih) + (size_t)ebase * 32;
    const int rowhalf = lane >> 5;        // 0 or 1
    const int col     = lane & 31;
    #pragma unroll
    for (int j = 0; j < 32; ++j) {
        float v = __shfl(val, 2 * j + rowhalf, 64);
        float4 v4 = make_float4(v, v, v, v);
        out[(size_t)(2 * j + rowhalf) * 32 + col] = v4;
    }
}

// ---------------------------------------------------------------------------
// Fallback path (ws too small): direct native-atomic scatter + fused dihedral.
// ---------------------------------------------------------------------------
__global__ void zero_du_kernel(float* __restrict__ du, int n) {
    int i = blockIdx.x * blockDim.x + threadIdx.x;
    if (i < n) du[i] = 0.0f;
}

__global__ void edge_scatter_kernel(const float* __restrict__ pos,
                                    const int* __restrict__ eidx,
                                    float* __restrict__ du) {
    int e = blockIdx.x * blockDim.x + threadIdx.x;
    if (e >= N_EDGES) return;
    int r = eidx[e];
    int c = eidx[N_EDGES + e];
    float dx = pos[c * 3 + 0] - pos[r * 3 + 0];
    float dy = pos[c * 3 + 1] - pos[r * 3 + 1];
    float dz = pos[c * 3 + 2] - pos[r * 3 + 2];
    float inv = 1.0f / (sqrtf(dx * dx + dy * dy + dz * dz) + 1e-8f);
    float ux = dx * inv, uy = dy * inv, uz = dz * inv;
    unsafeAtomicAdd(&du[r * 3 + 0],  ux);
    unsafeAtomicAdd(&du[r * 3 + 1],  uy);
    unsafeAtomicAdd(&du[r * 3 + 2],  uz);
    unsafeAtomicAdd(&du[c * 3 + 0], -ux);
    unsafeAtomicAdd(&du[c * 3 + 1], -uy);
    unsafeAtomicAdd(&du[c * 3 + 2], -uz);
}

__global__ void angular_kernel(const float* __restrict__ du,
                               float* __restrict__ ang) {
    int gid = blockIdx.x * blockDim.x + threadIdx.x;
    int node = gid >> 5;
    int c4   = gid & 31;
    float x = du[node * 3 + 0];
    float y = du[node * 3 + 1];
    float z = du[node * 3 + 2];
    float a = x * x + y * y + z * z;
    vfloat4 v4 = {a, a, a, a};
    __builtin_nontemporal_store(v4,
        reinterpret_cast<vfloat4*>(ang + (size_t)node * HIDDEN) + c4);
}

__global__ __launch_bounds__(256) void dihedral_fallback_kernel(
    const float* __restrict__ pos,
    const int* __restrict__ eidx,
    const float* __restrict__ du,
    float* __restrict__ dih)
{
    __shared__ float vals[256];
    const int e0 = blockIdx.x * 256;
    const int e  = e0 + threadIdx.x;
    {
        int r = eidx[e];
        int c = eidx[N_EDGES + e];
        float dx = pos[c * 3 + 0] - pos[r * 3 + 0];
        float dy = pos[c * 3 + 1] - pos[r * 3 + 1];
        float dz = pos[c * 3 + 2] - pos[r * 3 + 2];
        float inv = 1.0f / (sqrtf(dx * dx + dy * dy + dz * dz) + 1e-8f);
        float ux = dx * inv, uy = dy * inv, uz = dz * inv;
        float vix = du[r * 3 + 0], viy = du[r * 3 + 1], viz = du[r * 3 + 2];
        float vjx = du[c * 3 + 0], vjy = du[c * 3 + 1], vjz = du[c * 3 + 2];
        float dvi = vix * ux + viy * uy + viz * uz;
        float dvj = -(vjx * ux + vjy * uy + vjz * uz);
        float wix = vix - dvi * ux, wiy = viy - dvi * uy, wiz = viz - dvi * uz;
        float wjx = vjx + dvj * ux, wjy = vjy + dvj * uy, wjz = vjz + dvj * uz;
        vals[threadIdx.x] = wix * wjx + wiy * wjy + wiz * wjz;
    }
    __syncthreads();
    vfloat4* out = reinterpret_cast<vfloat4*>(dih + (size_t)e0 * HIDDEN);
    #pragma unroll
    for (int it = 0; it < 32; ++it) {
        int i = it * 256 + threadIdx.x;
        float v = vals[i >> 5];
        vfloat4 v4 = {v, v, v, v};
        __builtin_nontemporal_store(v4, out + i);
    }
}

// ---------------------------------------------------------------------------
extern "C" void kernel_launch(void* const* d_in, const int* in_sizes, int n_in,
                              void* d_out, int out_size, void* d_ws, size_t ws_size,
                              hipStream_t stream) {
    const float* pos  = (const float*)d_in[0];
    const int*   eidx = (const int*)d_in[1];

    float* out = (float*)d_out;
    float* ang = out;                                         // (N, 128)
    float* dih = out + (size_t)N_NODES * HIDDEN;              // (E, 128)
    float* du  = dih + (size_t)N_EDGES * HIDDEN;              // (N, 3)

    const size_t curWords  = (size_t)NBINS * CUR_STRIDE;
    const size_t tblWords  = (size_t)NPAD * 4;
    const size_t wsWords   = ws_size / 4;

    int cap = 0;
    if (wsWords > curWords + 2 * tblWords) {
        size_t avail = (wsWords - curWords - 2 * tblWords) / NBINS;
        avail &= ~(size_t)255;
        cap = (int)(avail < BIN_CAP_MAX ? avail : BIN_CAP_MAX);
    }

    if (cap >= BIN_CAP_MIN) {
        unsigned* cursors = (unsigned*)d_ws;
        float4*   pos4    = (float4*)((unsigned*)d_ws + curWords);
        float4*   du4     = (float4*)((unsigned*)d_ws + curWords + tblWords);
        unsigned* region  = (unsigned*)d_ws + curWords + 2 * tblWords;

        zero_cursors_kernel<<<1, NBINS, 0, stream>>>(cursors);
        bin_edges_kernel<<<A_BLOCKS, A_THREADS, 0, stream>>>(eidx, pos, cursors,
                                                             region, pos4, cap);
        accumulate_kernel<<<NBINS * 2, B_THREADS, 0, stream>>>(pos4, cursors,
                                                               region, cap,
                                                               du, ang, du4);
        dihedral_kernel<<<C_BLOCKS, C_THREADS, 0, stream>>>(pos4, du4, eidx, dih);
    } else {
        zero_du_kernel<<<(N_NODES * 3 + 255) / 256, 256, 0, stream>>>(du, N_NODES * 3);
        edge_scatter_kernel<<<(N_EDGES + 255) / 256, 256, 0, stream>>>(pos, eidx, du);
        angular_kernel<<<(N_NODES * 32) / 256, 256, 0, stream>>>(du, ang);
        dihedral_fallback_kernel<<<N_EDGES / 256, 256, 0, stream>>>(pos, eidx, du, dih);
    }
}

// Round 14
// 211.752 us; speedup vs baseline: 1.1273x; 1.1273x over previous
//
#include <hip/hip_runtime.h>
#include <math.h>

#define N_NODES 100000
#define N_EDGES 1600000
#define HIDDEN 128

// ---- binning geometry ------------------------------------------------------
#define NBINS      256
#define BIN_NODES  391        // 256*391 = 100096 >= 100000
#define HALF_NODES 196        // node-half split for B occupancy (196+195)
#define BIN_CAP_MAX 14336     // preferred cap; runtime-shrinks
#define BIN_CAP_MIN 13056     // below this, fall back
#define CUR_STRIDE 32         // cursors padded to 1 per 128B line
#define A_THREADS  1024
#define A_EPT      8
#define A_EPB      (A_THREADS * A_EPT)                    // 8192 edges/block
#define A_BLOCKS   ((N_EDGES + A_EPB - 1) / A_EPB)        // 196
#define B_THREADS  1024
#define NPAD       100096

// Fixed-point scale for LDS du accumulation (native ds_add_u32).
#define FP_SCALE   4194304.0f
#define FP_INV     (1.0f / 4194304.0f)

// Record layout: [26:17]=own-local node (9b), [16:0]=other node id (17b).

typedef float vfloat4 __attribute__((ext_vector_type(4)));

// ---------------------------------------------------------------------------
// Kernel Z: zero padded cursors.
// ---------------------------------------------------------------------------
__global__ void zero_cursors_kernel(unsigned* __restrict__ cur) {
    cur[threadIdx.x * CUR_STRIDE] = 0u;
}

// ---------------------------------------------------------------------------
// Kernel A: bin edges (8 edges/thread) + build pos4 with idle capacity.
// ---------------------------------------------------------------------------
__global__ __launch_bounds__(A_THREADS) void bin_edges_kernel(
    const int* __restrict__ eidx,
    const float* __restrict__ pos,
    unsigned* __restrict__ cursors,
    unsigned* __restrict__ region,
    float4* __restrict__ pos4,
    int cap)
{
    __shared__ unsigned cnt[NBINS];
    __shared__ unsigned base[NBINS];
    if (threadIdx.x < NBINS) cnt[threadIdx.x] = 0u;

    {
        int gid = blockIdx.x * A_THREADS + threadIdx.x;
        if (gid < N_NODES)
            pos4[gid] = make_float4(pos[gid * 3 + 0], pos[gid * 3 + 1],
                                    pos[gid * 3 + 2], 0.0f);
    }
    __syncthreads();

    const int eb = blockIdx.x * A_EPB + threadIdx.x * 2;

    bool     val[A_EPT];
    unsigned r[A_EPT], c[A_EPT], br[A_EPT], bc[A_EPT], orow[A_EPT], ocol[A_EPT];

    #pragma unroll
    for (int k = 0; k < A_EPT; k += 2) {
        int e = eb + k * A_THREADS;
        bool v = (e < N_EDGES);
        val[k] = v; val[k + 1] = v;
        if (v) {
            int2 rr = *reinterpret_cast<const int2*>(eidx + e);
            int2 cc = *reinterpret_cast<const int2*>(eidx + N_EDGES + e);
            r[k] = (unsigned)rr.x; r[k + 1] = (unsigned)rr.y;
            c[k] = (unsigned)cc.x; c[k + 1] = (unsigned)cc.y;
        }
    }
    #pragma unroll
    for (int k = 0; k < A_EPT; ++k) {
        if (val[k]) {
            br[k] = r[k] / BIN_NODES;
            bc[k] = c[k] / BIN_NODES;
            orow[k] = atomicAdd(&cnt[br[k]], 1u);
            ocol[k] = atomicAdd(&cnt[bc[k]], 1u);
        }
    }
    __syncthreads();

    if (threadIdx.x < NBINS)
        base[threadIdx.x] =
            atomicAdd(&cursors[threadIdx.x * CUR_STRIDE], cnt[threadIdx.x]);
    __syncthreads();

    #pragma unroll
    for (int k = 0; k < A_EPT; ++k) {
        if (val[k]) {
            region[(size_t)br[k] * cap + base[br[k]] + orow[k]] =
                ((r[k] - br[k] * BIN_NODES) << 17) | c[k];
            region[(size_t)bc[k] * cap + base[bc[k]] + ocol[k]] =
                ((c[k] - bc[k] * BIN_NODES) << 17) | r[k];
        }
    }
}

// ---------------------------------------------------------------------------
// Kernel B: two blocks per bin, int32 fixed-point LDS accumulate.
// ---------------------------------------------------------------------------
__device__ __forceinline__ void proc_rec(unsigned rec, unsigned half,
                                         const float4* __restrict__ posLDS4,
                                         const float4* __restrict__ pos4,
                                         int* __restrict__ acc) {
    unsigned local = rec >> 17;
    unsigned h = (local >= HALF_NODES) ? 1u : 0u;
    if (h != half) return;
    unsigned l = local - half * HALF_NODES;
    unsigned other = rec & 0x1FFFFu;
    float4 s = posLDS4[l];
    float4 p = pos4[other];
    float dx = p.x - s.x;
    float dy = p.y - s.y;
    float dz = p.z - s.z;
    float inv = 1.0f / (sqrtf(dx * dx + dy * dy + dz * dz) + 1e-8f);
    atomicAdd(&acc[l * 3 + 0], __float2int_rn(dx * inv * FP_SCALE));
    atomicAdd(&acc[l * 3 + 1], __float2int_rn(dy * inv * FP_SCALE));
    atomicAdd(&acc[l * 3 + 2], __float2int_rn(dz * inv * FP_SCALE));
}

__global__ __launch_bounds__(B_THREADS) void accumulate_kernel(
    const float4* __restrict__ pos4,
    const unsigned* __restrict__ cursors,
    const unsigned* __restrict__ region,
    int cap,
    float* __restrict__ du,
    float* __restrict__ ang,
    float4* __restrict__ du4)
{
    __shared__ int    acc[HALF_NODES * 3];
    __shared__ float4 posLDS4[HALF_NODES];
    const unsigned b    = blockIdx.x >> 1;
    const unsigned half = blockIdx.x & 1;
    const unsigned g0   = b * BIN_NODES + half * HALF_NODES;
    const int maxh = half ? (BIN_NODES - HALF_NODES) : HALF_NODES;
    const int rem  = (int)N_NODES - (int)g0;
    const unsigned nh = (unsigned)max(0, min(maxh, rem));

    for (int i = threadIdx.x; i < HALF_NODES * 3; i += B_THREADS) acc[i] = 0;
    for (unsigned i = threadIdx.x; i < nh; i += B_THREADS)
        posLDS4[i] = pos4[g0 + i];
    __syncthreads();

    const unsigned n = cursors[b * CUR_STRIDE];
    const unsigned* __restrict__ reg = region + (size_t)b * cap;
    const unsigned n4 = n & ~3u;

    for (unsigned i = threadIdx.x * 4; i < n4; i += B_THREADS * 4) {
        uint4 rc = *reinterpret_cast<const uint4*>(reg + i);
        proc_rec(rc.x, half, posLDS4, pos4, acc);
        proc_rec(rc.y, half, posLDS4, pos4, acc);
        proc_rec(rc.z, half, posLDS4, pos4, acc);
        proc_rec(rc.w, half, posLDS4, pos4, acc);
    }
    for (unsigned i = n4 + threadIdx.x; i < n; i += B_THREADS)
        proc_rec(reg[i], half, posLDS4, pos4, acc);
    __syncthreads();

    for (unsigned i = threadIdx.x; i < nh * 3; i += B_THREADS)
        du[(size_t)g0 * 3 + i] = (float)acc[i] * FP_INV;

    for (unsigned i = threadIdx.x; i < nh; i += B_THREADS) {
        float x = (float)acc[i * 3 + 0] * FP_INV;
        float y = (float)acc[i * 3 + 1] * FP_INV;
        float z = (float)acc[i * 3 + 2] * FP_INV;
        du4[g0 + i] = make_float4(x, y, z, x * x + y * y + z * z);
    }

    for (unsigned j = threadIdx.x; j < nh * 32; j += B_THREADS) {
        unsigned node = j >> 5, c4 = j & 31;
        float x = (float)acc[node * 3 + 0] * FP_INV;
        float y = (float)acc[node * 3 + 1] * FP_INV;
        float z = (float)acc[node * 3 + 2] * FP_INV;
        float a = x * x + y * y + z * z;
        vfloat4 v4 = {a, a, a, a};
        __builtin_nontemporal_store(v4,
            reinterpret_cast<vfloat4*>(ang + (size_t)(g0 + node) * HIDDEN) + c4);
    }
}

// ---------------------------------------------------------------------------
// Kernel C: dihedral via pos4/du4 vector gathers; LDS broadcast + NT float4
// stores (R12's best-measured fill structure).
// w_ij . w_ji = v_i.v_j - (v_i.u)(v_j.u)(2 - u.u)  [exact algebra]
// ---------------------------------------------------------------------------
__global__ __launch_bounds__(256) void dihedral_kernel(
    const float4* __restrict__ pos4,
    const float4* __restrict__ du4,
    const int* __restrict__ eidx,
    float* __restrict__ dih)
{
    __shared__ float vals[256];
    const int e0 = blockIdx.x * 256;
    const int e  = e0 + threadIdx.x;

    {
        int r = eidx[e];
        int c = eidx[N_EDGES + e];
        float4 pr = pos4[r];
        float4 pc = pos4[c];
        float4 vi = du4[r];
        float4 vj = du4[c];

        float dx = pc.x - pr.x, dy = pc.y - pr.y, dz = pc.z - pr.z;
        float inv = 1.0f / (sqrtf(dx * dx + dy * dy + dz * dz) + 1e-8f);
        float ux = dx * inv, uy = dy * inv, uz = dz * inv;

        float a  = vi.x * ux + vi.y * uy + vi.z * uz;
        float b  = vj.x * ux + vj.y * uy + vj.z * uz;
        float vv = vi.x * vj.x + vi.y * vj.y + vi.z * vj.z;
        float uu = ux * ux + uy * uy + uz * uz;

        vals[threadIdx.x] = vv - a * b * (2.0f - uu);
    }
    __syncthreads();

    vfloat4* out = reinterpret_cast<vfloat4*>(dih + (size_t)e0 * HIDDEN);
    #pragma unroll
    for (int it = 0; it < 32; ++it) {
        int i = it * 256 + threadIdx.x;
        float v = vals[i >> 5];
        vfloat4 v4 = {v, v, v, v};
        __builtin_nontemporal_store(v4, out + i);
    }
}

// ---------------------------------------------------------------------------
// Fallback path (ws too small): direct native-atomic scatter + fused dihedral.
// ---------------------------------------------------------------------------
__global__ void zero_du_kernel(float* __restrict__ du, int n) {
    int i = blockIdx.x * blockDim.x + threadIdx.x;
    if (i < n) du[i] = 0.0f;
}

__global__ void edge_scatter_kernel(const float* __restrict__ pos,
                                    const int* __restrict__ eidx,
                                    float* __restrict__ du) {
    int e = blockIdx.x * blockDim.x + threadIdx.x;
    if (e >= N_EDGES) return;
    int r = eidx[e];
    int c = eidx[N_EDGES + e];
    float dx = pos[c * 3 + 0] - pos[r * 3 + 0];
    float dy = pos[c * 3 + 1] - pos[r * 3 + 1];
    float dz = pos[c * 3 + 2] - pos[r * 3 + 2];
    float inv = 1.0f / (sqrtf(dx * dx + dy * dy + dz * dz) + 1e-8f);
    float ux = dx * inv, uy = dy * inv, uz = dz * inv;
    unsafeAtomicAdd(&du[r * 3 + 0],  ux);
    unsafeAtomicAdd(&du[r * 3 + 1],  uy);
    unsafeAtomicAdd(&du[r * 3 + 2],  uz);
    unsafeAtomicAdd(&du[c * 3 + 0], -ux);
    unsafeAtomicAdd(&du[c * 3 + 1], -uy);
    unsafeAtomicAdd(&du[c * 3 + 2], -uz);
}

__global__ void angular_kernel(const float* __restrict__ du,
                               float* __restrict__ ang) {
    int gid = blockIdx.x * blockDim.x + threadIdx.x;
    int node = gid >> 5;
    int c4   = gid & 31;
    float x = du[node * 3 + 0];
    float y = du[node * 3 + 1];
    float z = du[node * 3 + 2];
    float a = x * x + y * y + z * z;
    vfloat4 v4 = {a, a, a, a};
    __builtin_nontemporal_store(v4,
        reinterpret_cast<vfloat4*>(ang + (size_t)node * HIDDEN) + c4);
}

__global__ __launch_bounds__(256) void dihedral_fallback_kernel(
    const float* __restrict__ pos,
    const int* __restrict__ eidx,
    const float* __restrict__ du,
    float* __restrict__ dih)
{
    __shared__ float vals[256];
    const int e0 = blockIdx.x * 256;
    const int e  = e0 + threadIdx.x;
    {
        int r = eidx[e];
        int c = eidx[N_EDGES + e];
        float dx = pos[c * 3 + 0] - pos[r * 3 + 0];
        float dy = pos[c * 3 + 1] - pos[r * 3 + 1];
        float dz = pos[c * 3 + 2] - pos[r * 3 + 2];
        float inv = 1.0f / (sqrtf(dx * dx + dy * dy + dz * dz) + 1e-8f);
        float ux = dx * inv, uy = dy * inv, uz = dz * inv;
        float vix = du[r * 3 + 0], viy = du[r * 3 + 1], viz = du[r * 3 + 2];
        float vjx = du[c * 3 + 0], vjy = du[c * 3 + 1], vjz = du[c * 3 + 2];
        float dvi = vix * ux + viy * uy + viz * uz;
        float dvj = -(vjx * ux + vjy * uy + vjz * uz);
        float wix = vix - dvi * ux, wiy = viy - dvi * uy, wiz = viz - dvi * uz;
        float wjx = vjx + dvj * ux, wjy = vjy + dvj * uy, wjz = vjz + dvj * uz;
        vals[threadIdx.x] = wix * wjx + wiy * wjy + wiz * wjz;
    }
    __syncthreads();
    vfloat4* out = reinterpret_cast<vfloat4*>(dih + (size_t)e0 * HIDDEN);
    #pragma unroll
    for (int it = 0; it < 32; ++it) {
        int i = it * 256 + threadIdx.x;
        float v = vals[i >> 5];
        vfloat4 v4 = {v, v, v, v};
        __builtin_nontemporal_store(v4, out + i);
    }
}

// ---------------------------------------------------------------------------
extern "C" void kernel_launch(void* const* d_in, const int* in_sizes, int n_in,
                              void* d_out, int out_size, void* d_ws, size_t ws_size,
                              hipStream_t stream) {
    const float* pos  = (const float*)d_in[0];
    const int*   eidx = (const int*)d_in[1];

    float* out = (float*)d_out;
    float* ang = out;                                         // (N, 128)
    float* dih = out + (size_t)N_NODES * HIDDEN;              // (E, 128)
    float* du  = dih + (size_t)N_EDGES * HIDDEN;              // (N, 3)

    const size_t curWords  = (size_t)NBINS * CUR_STRIDE;
    const size_t tblWords  = (size_t)NPAD * 4;
    const size_t wsWords   = ws_size / 4;

    int cap = 0;
    if (wsWords > curWords + 2 * tblWords) {
        size_t avail = (wsWords - curWords - 2 * tblWords) / NBINS;
        avail &= ~(size_t)255;
        cap = (int)(avail < BIN_CAP_MAX ? avail : BIN_CAP_MAX);
    }

    if (cap >= BIN_CAP_MIN) {
        unsigned* cursors = (unsigned*)d_ws;
        float4*   pos4    = (float4*)((unsigned*)d_ws + curWords);
        float4*   du4     = (float4*)((unsigned*)d_ws + curWords + tblWords);
        unsigned* region  = (unsigned*)d_ws + curWords + 2 * tblWords;

        zero_cursors_kernel<<<1, NBINS, 0, stream>>>(cursors);
        bin_edges_kernel<<<A_BLOCKS, A_THREADS, 0, stream>>>(eidx, pos, cursors,
                                                             region, pos4, cap);
        accumulate_kernel<<<NBINS * 2, B_THREADS, 0, stream>>>(pos4, cursors,
                                                               region, cap,
                                                               du, ang, du4);
        dihedral_kernel<<<N_EDGES / 256, 256, 0, stream>>>(pos4, du4, eidx, dih);
    } else {
        zero_du_kernel<<<(N_NODES * 3 + 255) / 256, 256, 0, stream>>>(du, N_NODES * 3);
        edge_scatter_kernel<<<(N_EDGES + 255) / 256, 256, 0, stream>>>(pos, eidx, du);
        angular_kernel<<<(N_NODES * 32) / 256, 256, 0, stream>>>(du, ang);
        dihedral_fallback_kernel<<<N_EDGES / 256, 256, 0, stream>>>(pos, eidx, du, dih);
    }
}